// Round 8
// baseline (545.445 us; speedup 1.0000x reference)
//
#include <hip/hip_runtime.h>
#include <hip/hip_bf16.h>
#include <math.h>

// Problem constants (fixed by the reference).
#define N_NODES 100000
#define N_EDGES 1600000
#define DF      128
#define EPSV    1e-5f
#define SLOPE   0.01f
#define M_TOT   (N_NODES * DF)   // 12,800,000 elements

#define HG    512                // histogram blocks (E/HG = 3125 edges each)
#define EPB   (N_EDGES / HG)     // 3125
#define NBIN  391                // ceil(N_NODES / 256); bin = dst >> 8

typedef __hip_bfloat16 bf16;
typedef __attribute__((ext_vector_type(8))) short short8;   // 8 bf16 = 4 VGPRs (MFMA A/B frag)
typedef __attribute__((ext_vector_type(4))) float f32x4;    // MFMA C/D frag

// ---------------------------------------------------------------------------
// Runtime dtype detection + bucket zeroing.
// ---------------------------------------------------------------------------
__global__ void k_detect(const unsigned int* __restrict__ yw32, int* __restrict__ flagp,
                         int* __restrict__ bucketsI)
{
    __shared__ int cnt;
    const int tid = threadIdx.x;
    if (tid == 0) cnt = 0;
    for (int i = tid; i < 1536; i += 256) bucketsI[i] = 0;
    __syncthreads();
    unsigned w = yw32[tid];                  // 256 words sampled
    int e = (w >> 7) & 0xFF;
    if (e >= 96 && e <= 140) atomicAdd(&cnt, 1);
    __syncthreads();
    if (tid == 0) flagp[0] = (cnt >= 150) ? 1 : 0;   // 1 = bf16 inputs
}

// ---------------------------------------------------------------------------
// Edge decode: handles both int32 and int64 layouts of edge_index[2,E].
// ---------------------------------------------------------------------------
__device__ __forceinline__ void edge_decode(const int* __restrict__ ei, int e,
                                            int& s, int& d)
{
    bool is64 = ((ei[1] | ei[3] | ei[5] | ei[7]) == 0);
    if (is64) { s = ei[2 * e]; d = ei[2 * (N_EDGES + e)]; }
    else      { s = ei[e];     d = ei[N_EDGES + e];       }
}

// ---------------------------------------------------------------------------
// CSR build, pass 1: per-block LDS histogram over 391 coarse bins (dst>>8).
// ZERO global atomics. y -> bf16 conversion fused.
// ---------------------------------------------------------------------------
__global__ __launch_bounds__(256) void k_hist(
    const void* __restrict__ yin, bf16* __restrict__ yw,
    const int* __restrict__ flagp, const int* __restrict__ ei,
    int* __restrict__ histG)
{
    __shared__ int h[NBIN];
    const int tid = threadIdx.x, b = blockIdx.x;
    for (int i = tid; i < NBIN; i += 256) h[i] = 0;
    __syncthreads();

    const int e0 = b * EPB;
    for (int e = e0 + tid; e < e0 + EPB; e += 256) {
        int s, d;
        edge_decode(ei, e, s, d);
        if ((unsigned)s < N_NODES && (unsigned)d < N_NODES)
            atomicAdd(&h[d >> 8], 1);
    }

    // Fused cvt: grid-stride over 1.6M uint4 chunks (8 bf16 each).
    const int isbf = flagp[0];
    for (long t = (long)b * 256 + tid; t < (M_TOT / 8); t += (long)HG * 256) {
        float f[8];
        if (isbf) {
            uint4 v = reinterpret_cast<const uint4*>(yin)[t];
            const bf16* sp = reinterpret_cast<const bf16*>(&v);
#pragma unroll
            for (int j = 0; j < 8; ++j) f[j] = __bfloat162float(sp[j]);
        } else {
            float4 v0 = reinterpret_cast<const float4*>(yin)[2 * t];
            float4 v1 = reinterpret_cast<const float4*>(yin)[2 * t + 1];
            f[0] = v0.x; f[1] = v0.y; f[2] = v0.z; f[3] = v0.w;
            f[4] = v1.x; f[5] = v1.y; f[6] = v1.z; f[7] = v1.w;
        }
        uint4 ov;
        bf16* o = reinterpret_cast<bf16*>(&ov);
#pragma unroll
        for (int j = 0; j < 8; ++j) {
            float x = f[j];
            if (!isfinite(x)) x = 0.f;
            o[j] = __float2bfloat16(x);
        }
        reinterpret_cast<uint4*>(yw)[t] = ov;
    }

    __syncthreads();
    for (int i = tid; i < NBIN; i += 256) histG[i * HG + b] = h[i];
}

// Pass 2: per-bin exclusive scan over the 512 blocks (in place) + bin total.
__global__ void k_hscan1(int* __restrict__ histG, int* __restrict__ binTotal)
{
    __shared__ int sc[512];
    const int bin = blockIdx.x, tid = threadIdx.x;
    int v = histG[bin * HG + tid];
    sc[tid] = v;
    __syncthreads();
    for (int off = 1; off < 512; off <<= 1) {
        int t = (tid >= off) ? sc[tid - off] : 0;
        __syncthreads();
        sc[tid] += t;
        __syncthreads();
    }
    histG[bin * HG + tid] = sc[tid] - v;      // exclusive over blocks
    if (tid == 511) binTotal[bin] = sc[511];
}

// Pass 3: inline bin-total scan; scatter packed (dstLow8<<17 | src).
__global__ __launch_bounds__(256) void k_scatter(
    const int* __restrict__ ei, const int* __restrict__ histG,
    const int* __restrict__ binTotal, int* __restrict__ binStart,
    int* __restrict__ binned)
{
    __shared__ int sc[512];
    __shared__ int base[NBIN];
    __shared__ int cur[NBIN];
    const int tid = threadIdx.x, b = blockIdx.x;

    {
        int v0 = (tid < NBIN) ? binTotal[tid] : 0;
        int v1 = (tid + 256 < NBIN) ? binTotal[tid + 256] : 0;
        sc[tid] = v0; sc[tid + 256] = v1;
        __syncthreads();
        for (int off = 1; off < 512; off <<= 1) {
            int a  = (tid >= off) ? sc[tid - off] : 0;
            int b2 = (tid + 256 >= off) ? sc[tid + 256 - off] : 0;
            __syncthreads();
            sc[tid] += a; sc[tid + 256] += b2;
            __syncthreads();
        }
    }
    for (int i = tid; i < NBIN; i += 256) {
        int ex = sc[i] - binTotal[i];         // exclusive prefix
        base[i] = ex + histG[i * HG + b];
        cur[i]  = 0;
        if (b == 0) binStart[i] = ex;         // publish for k_bin
    }
    __syncthreads();

    const int e0 = b * EPB;
    for (int e = e0 + tid; e < e0 + EPB; e += 256) {
        int s, d;
        edge_decode(ei, e, s, d);
        if ((unsigned)s < N_NODES && (unsigned)d < N_NODES) {
            int bin = d >> 8;
            int r = atomicAdd(&cur[bin], 1);
            binned[base[bin] + r] = ((d & 255) << 17) | s;
        }
    }
}

// Pass 4: one block per bin -> exact per-node CSR (degcnt, offs, edst).
__global__ __launch_bounds__(256) void k_bin(
    const int* __restrict__ binned, const int* __restrict__ binStart,
    const int* __restrict__ binTotal, int* __restrict__ edst,
    int* __restrict__ degcnt, int* __restrict__ offs)
{
    __shared__ int hloc[256];
    __shared__ int lofs[256];
    __shared__ int sc[256];
    const int bin = blockIdx.x, tid = threadIdx.x;
    const int bbase = binStart[bin], cnt = binTotal[bin];

    hloc[tid] = 0;
    __syncthreads();
    for (int i = tid; i < cnt; i += 256)
        atomicAdd(&hloc[binned[bbase + i] >> 17], 1);
    __syncthreads();

    const int deg = hloc[tid];
    sc[tid] = deg;
    __syncthreads();
    for (int off = 1; off < 256; off <<= 1) {
        int t = (tid >= off) ? sc[tid - off] : 0;
        __syncthreads();
        sc[tid] += t;
        __syncthreads();
    }
    const int ex = sc[tid] - deg;
    lofs[tid] = ex;
    const int node = bin * 256 + tid;
    if (node < N_NODES) {
        degcnt[node] = deg;
        offs[node]   = bbase + ex;
    }
    hloc[tid] = 0;          // reuse as per-node cursor
    __syncthreads();

    for (int i = tid; i < cnt; i += 256) {
        int v = binned[bbase + i];
        int n = v >> 17;
        int r = atomicAdd(&hloc[n], 1);
        edst[bbase + lofs[n] + r] = v & 0x1FFFF;
    }
}

// ---------------------------------------------------------------------------
// Weights convert+transpose (W[l][k][n] -> Wt[mat][n][k]) for MFMA B.
// Block 576 additionally packs the small params.
// ---------------------------------------------------------------------------
__global__ void k_wt(const void* __restrict__ W1, const void* __restrict__ W2,
                     const void* __restrict__ W3, bf16* __restrict__ Wt,
                     const void* __restrict__ b1, const void* __restrict__ b3,
                     const void* __restrict__ lnw, const void* __restrict__ lnb,
                     bf16* __restrict__ prm, const int* __restrict__ flagp)
{
    const int isbf = flagp[0];
    if (blockIdx.x == 576) {
        for (int i = threadIdx.x; i < 1536; i += 256) {
            int which = i / 384, r = i - which * 384;
            const void* src = (which == 0) ? b1 : (which == 1) ? b3
                            : (which == 2) ? lnw : lnb;
            float v = isbf ? __bfloat162float(reinterpret_cast<const bf16*>(src)[r])
                           : reinterpret_cast<const float*>(src)[r];
            if (!isfinite(v)) v = 0.f;
            prm[i] = __float2bfloat16(v);
        }
        return;
    }
    int idx = blockIdx.x * 256 + threadIdx.x;      // < 9*16384 = 147456
    int mat = idx >> 14;
    int r   = idx & 16383;
    int k   = r >> 7, n = r & 127;
    int l = mat / 3, which = mat - l * 3;
    const void* src = (which == 0) ? W1 : (which == 1 ? W2 : W3);
    size_t ofs = (size_t)l * 16384 + (size_t)k * 128 + n;
    float v = isbf ? __bfloat162float(reinterpret_cast<const bf16*>(src)[ofs])
                   : reinterpret_cast<const float*>(src)[ofs];
    if (!isfinite(v)) v = 0.f;
    Wt[((size_t)mat << 14) + (size_t)n * 128 + k] = __float2bfloat16(v);
}

// ---------------------------------------------------------------------------
// Inline LN-stats reduce: 256 threads fold the 256 bucket pairs of `layer`
// into {mean, inv} broadcast via LDS.
// ---------------------------------------------------------------------------
__device__ __forceinline__ void stats_reduce(
    const float* __restrict__ buckets, int layer, int tid,
    double* redS, float* s_mean, float* s_inv)
{
    double s1 = (double)buckets[layer * 512 + tid * 2];
    double s2 = (double)buckets[layer * 512 + tid * 2 + 1];
#pragma unroll
    for (int m = 1; m < 64; m <<= 1) {
        s1 += __shfl_xor(s1, m);
        s2 += __shfl_xor(s2, m);
    }
    const int wv = tid >> 6;
    if ((tid & 63) == 0) { redS[wv] = s1; redS[4 + wv] = s2; }
    __syncthreads();
    if (tid == 0) {
        double S1 = redS[0] + redS[1] + redS[2] + redS[3];
        double S2 = redS[4] + redS[5] + redS[6] + redS[7];
        double mean, inv;
        if (isfinite(S1) && isfinite(S2)) {
            const double M = (double)M_TOT;
            mean = S1 / M;
            double var = S2 / M - mean * mean;
            if (!(var > 0.0)) var = 0.0;
            inv = 1.0 / (sqrt(var) + (double)EPSV);
        } else {
            mean = 0.0; inv = 1.0;
        }
        *s_mean = (float)mean;
        *s_inv  = (float)inv;
    }
    __syncthreads();
}

// ---------------------------------------------------------------------------
// Fused triple GEMM, 128-row M-tile (was 64): halves per-output B-staging
// bytes, ds_read traffic, and barrier count. LDS = 69.6 KB -> 2 blocks/CU.
// Each wave computes 2 row-fragments (32 rows) x 128 cols.
//   pass 1: accB = y@W2 ; pass 2: accC = y@W3 -> cmb = accC + b3 - deg*accB
//   pass 3: accA = y@W1 -> aBuf = accA + b1
// ---------------------------------------------------------------------------
#define GEMM_M 128

__global__ __launch_bounds__(256) void k_gemm3(
    bf16* __restrict__ yw, const bf16* __restrict__ hprev,
    const float* __restrict__ buckets, const bf16* __restrict__ Wt,
    const bf16* __restrict__ prm, const int* __restrict__ degcnt,
    bf16* __restrict__ aBuf, bf16* __restrict__ cmb, int layer)
{
    __shared__ bf16 Asm[128][136];    // 34,816 B ; +8 pad keeps 16B align
    __shared__ bf16 Bsm[128][136];    // 34,816 B
    __shared__ double redS[8];
    __shared__ float s_mean, s_inv;

    const int tid = threadIdx.x;
    const long r0 = (long)blockIdx.x * GEMM_M;

    const uint4* gy = reinterpret_cast<const uint4*>(yw);

    if (layer == 0) {
        // Plain A-staging: 128 rows x 16 chunks = 2048.
#pragma unroll
        for (int it = 0; it < 8; ++it) {
            int chunk = it * 256 + tid;
            int row = chunk >> 4, colc = (chunk & 15) * 8;
            uint4 v = make_uint4(0, 0, 0, 0);
            long grow = r0 + row;
            if (grow < N_NODES) v = gy[grow * 16 + (chunk & 15)];
            *reinterpret_cast<uint4*>(&Asm[row][colc]) = v;
        }
    } else {
        stats_reduce(buckets, layer - 1, tid, redS, &s_mean, &s_inv);
        const float mean = s_mean;
        const float inv  = s_inv;
        // Fused: y_new = y_old + leaky(norm(h_prev)); stage + write back.
        const bf16* lnwc = prm + 768  + (layer - 1) * 128;
        const bf16* lnbc = prm + 1152 + (layer - 1) * 128;
        const uint4* gh = reinterpret_cast<const uint4*>(hprev);
#pragma unroll
        for (int it = 0; it < 8; ++it) {
            int chunk = it * 256 + tid;
            int row = chunk >> 4, c16 = chunk & 15, colc = c16 * 8;
            long grow = r0 + row;
            uint4 ov = make_uint4(0, 0, 0, 0);
            if (grow < N_NODES) {
                uint4 hv = gh[grow * 16 + c16];
                uint4 yv = gy[grow * 16 + c16];
                const bf16* h8 = reinterpret_cast<const bf16*>(&hv);
                const bf16* y8 = reinterpret_cast<const bf16*>(&yv);
                bf16* o8 = reinterpret_cast<bf16*>(&ov);
#pragma unroll
                for (int jj = 0; jj < 8; ++jj) {
                    float g = __bfloat162float(lnwc[colc + jj]);
                    float b = __bfloat162float(lnbc[colc + jj]);
                    float hh = (__bfloat162float(h8[jj]) - mean) * inv * g + b;
                    hh = (hh >= 0.f) ? hh : SLOPE * hh;
                    o8[jj] = __float2bfloat16(__bfloat162float(y8[jj]) + hh);
                }
                reinterpret_cast<uint4*>(yw)[grow * 16 + c16] = ov;
            }
            *reinterpret_cast<uint4*>(&Asm[row][colc]) = ov;
        }
    }

#define STAGE_B(MATIDX)                                                          \
    {                                                                            \
        const uint4* gw = reinterpret_cast<const uint4*>(Wt + ((size_t)(MATIDX) << 14)); \
        _Pragma("unroll")                                                        \
        for (int it = 0; it < 8; ++it) {                                         \
            int chunk = it * 256 + tid;                                          \
            *reinterpret_cast<uint4*>(&Bsm[chunk >> 4][(chunk & 15) * 8]) = gw[chunk]; \
        }                                                                        \
    }

    const int wave = tid >> 6, lane = tid & 63;
    const int lm = lane & 15, quad = lane >> 4;
    const int mrow0 = wave * 32 + lm;         // row-frag 0
    const int mrow1 = wave * 32 + 16 + lm;    // row-frag 1

    f32x4 accB[2][8], accC[2][8];
#pragma unroll
    for (int rf = 0; rf < 2; ++rf)
#pragma unroll
        for (int nt = 0; nt < 8; ++nt) {
            accB[rf][nt] = (f32x4){0.f, 0.f, 0.f, 0.f};
            accC[rf][nt] = (f32x4){0.f, 0.f, 0.f, 0.f};
        }

    // ---- pass 1: W2 ----
    STAGE_B(layer * 3 + 1);
    __syncthreads();
#pragma unroll
    for (int kk = 0; kk < 4; ++kk) {
        const int kb = kk * 32 + quad * 8;
        short8 afr0 = *reinterpret_cast<const short8*>(&Asm[mrow0][kb]);
        short8 afr1 = *reinterpret_cast<const short8*>(&Asm[mrow1][kb]);
#pragma unroll
        for (int nt = 0; nt < 8; ++nt) {
            short8 bfr = *reinterpret_cast<const short8*>(&Bsm[nt * 16 + lm][kb]);
            accB[0][nt] = __builtin_amdgcn_mfma_f32_16x16x32_bf16(afr0, bfr, accB[0][nt], 0, 0, 0);
            accB[1][nt] = __builtin_amdgcn_mfma_f32_16x16x32_bf16(afr1, bfr, accB[1][nt], 0, 0, 0);
        }
    }
    __syncthreads();

    // ---- pass 2: W3 ----
    STAGE_B(layer * 3 + 2);
    __syncthreads();
#pragma unroll
    for (int kk = 0; kk < 4; ++kk) {
        const int kb = kk * 32 + quad * 8;
        short8 afr0 = *reinterpret_cast<const short8*>(&Asm[mrow0][kb]);
        short8 afr1 = *reinterpret_cast<const short8*>(&Asm[mrow1][kb]);
#pragma unroll
        for (int nt = 0; nt < 8; ++nt) {
            short8 bfr = *reinterpret_cast<const short8*>(&Bsm[nt * 16 + lm][kb]);
            accC[0][nt] = __builtin_amdgcn_mfma_f32_16x16x32_bf16(afr0, bfr, accC[0][nt], 0, 0, 0);
            accC[1][nt] = __builtin_amdgcn_mfma_f32_16x16x32_bf16(afr1, bfr, accC[1][nt], 0, 0, 0);
        }
    }

    // cmb epilogue.  C/D layout: col = lane&15, row = quad*4 + reg.
    const bf16* b3c = prm + 384 + layer * 128;
#pragma unroll
    for (int rf = 0; rf < 2; ++rf) {
#pragma unroll
        for (int i = 0; i < 4; ++i) {
            long row = r0 + wave * 32 + rf * 16 + quad * 4 + i;
            if (row < N_NODES) {
                float degf = (float)degcnt[row];
#pragma unroll
                for (int nt = 0; nt < 8; ++nt) {
                    int col = nt * 16 + lm;
                    float v = accC[rf][nt][i] + __bfloat162float(b3c[col])
                            - degf * accB[rf][nt][i];
                    cmb[row * 128 + col] = __float2bfloat16(v);
                }
            }
        }
    }
    __syncthreads();

    // ---- pass 3: W1 (reuse accB) ----
    STAGE_B(layer * 3 + 0);
    __syncthreads();
#pragma unroll
    for (int rf = 0; rf < 2; ++rf)
#pragma unroll
        for (int nt = 0; nt < 8; ++nt) accB[rf][nt] = (f32x4){0.f, 0.f, 0.f, 0.f};
#pragma unroll
    for (int kk = 0; kk < 4; ++kk) {
        const int kb = kk * 32 + quad * 8;
        short8 afr0 = *reinterpret_cast<const short8*>(&Asm[mrow0][kb]);
        short8 afr1 = *reinterpret_cast<const short8*>(&Asm[mrow1][kb]);
#pragma unroll
        for (int nt = 0; nt < 8; ++nt) {
            short8 bfr = *reinterpret_cast<const short8*>(&Bsm[nt * 16 + lm][kb]);
            accB[0][nt] = __builtin_amdgcn_mfma_f32_16x16x32_bf16(afr0, bfr, accB[0][nt], 0, 0, 0);
            accB[1][nt] = __builtin_amdgcn_mfma_f32_16x16x32_bf16(afr1, bfr, accB[1][nt], 0, 0, 0);
        }
    }
    const bf16* b1c = prm + layer * 128;
#pragma unroll
    for (int rf = 0; rf < 2; ++rf) {
#pragma unroll
        for (int i = 0; i < 4; ++i) {
            long row = r0 + wave * 32 + rf * 16 + quad * 4 + i;
            if (row < N_NODES) {
#pragma unroll
                for (int nt = 0; nt < 8; ++nt) {
                    int col = nt * 16 + lm;
                    aBuf[row * 128 + col] =
                        __float2bfloat16(accB[rf][nt][i] + __bfloat162float(b1c[col]));
                }
            }
        }
    }
#undef STAGE_B
}

// ---------------------------------------------------------------------------
// Edge aggregation + h assembly (in place over cmb) + LN partial stats.
// R7 config (best measured: 67 us): row-major uint4 gathers, persistent
// waves, 4-deep ILP, cross-node rotation prefetch, deferred stats.
// ---------------------------------------------------------------------------
#define AGG_BLOCKS 2048
#define AGG_WAVES  (AGG_BLOCKS * 4)

__global__ __launch_bounds__(256, 8) void k_agg(
    const bf16* __restrict__ aBuf, bf16* __restrict__ cmb,
    const int* __restrict__ offs, const int* __restrict__ degcnt,
    const int* __restrict__ edst, float* __restrict__ buckets, int layer)
{
    const int tid  = threadIdx.x;
    const int lane = tid & 63;
    const int el   = lane >> 4;         // edge slot (0..3)
    const int fb   = lane & 15;         // feature block (8 bf16 = 16 B)
    const int wid  = __builtin_amdgcn_readfirstlane((int)(blockIdx.x * 4) + (tid >> 6));

    const uint4* A4 = reinterpret_cast<const uint4*>(aBuf);

    float s1w = 0.f, s2w = 0.f;         // per-lane LN stats over all our nodes

#define ACC8(v)                                                                \
    {                                                                          \
        const unsigned* _u = reinterpret_cast<const unsigned*>(&(v));          \
        _Pragma("unroll")                                                      \
        for (int _d = 0; _d < 4; ++_d) {                                       \
            acc[2 * _d]     += __uint_as_float(_u[_d] << 16);                  \
            acc[2 * _d + 1] += __uint_as_float(_u[_d] & 0xffff0000u);          \
        }                                                                      \
    }

    int node  = wid;                      // wid < 8192 << N_NODES, always valid
    int start = offs[node];
    int deg   = degcnt[node];
    while (node < N_NODES) {
        // Rotation prefetch: next node's CSR header resolves under this
        // node's gather chain.
        const int nxt = node + AGG_WAVES;
        int nstart = 0, ndeg = 0;
        if (nxt < N_NODES) { nstart = offs[nxt]; ndeg = degcnt[nxt]; }

        // Prefetch this node's cmb row (issues before the gather chain).
        const uint4 cv = reinterpret_cast<const uint4*>(cmb)[(size_t)node * 16 + fb];

        float acc[8];
#pragma unroll
        for (int i = 0; i < 8; ++i) acc[i] = 0.f;

        // Lane slot el covers indices j = el, el+4, el+8, ... (< deg).
        int j = el;
        for (; j + 12 < deg; j += 16) {       // 4 gathers in flight
            int e0 = edst[start + j];
            int e1 = edst[start + j + 4];
            int e2 = edst[start + j + 8];
            int e3 = edst[start + j + 12];
            uint4 v0 = A4[(size_t)e0 * 16 + fb];
            uint4 v1 = A4[(size_t)e1 * 16 + fb];
            uint4 v2 = A4[(size_t)e2 * 16 + fb];
            uint4 v3 = A4[(size_t)e3 * 16 + fb];
            ACC8(v0); ACC8(v1); ACC8(v2); ACC8(v3);
        }
        if (j + 4 < deg) {                    // 2 gathers in flight
            int e0 = edst[start + j];
            int e1 = edst[start + j + 4];
            uint4 v0 = A4[(size_t)e0 * 16 + fb];
            uint4 v1 = A4[(size_t)e1 * 16 + fb];
            ACC8(v0); ACC8(v1);
            j += 8;
        }
        if (j < deg) {                        // last single
            int e0 = edst[start + j];
            uint4 v0 = A4[(size_t)e0 * 16 + fb];
            ACC8(v0);
        }

        // Reduce across the 4 edge slots (lane bits 4,5).
#pragma unroll
        for (int i = 0; i < 8; ++i) {
            acc[i] += __shfl_xor(acc[i], 16);
            acc[i] += __shfl_xor(acc[i], 32);
        }

        // h = agg + cmb row; all lanes compute (identical across el groups).
        const unsigned* cu = reinterpret_cast<const unsigned*>(&cv);
        float h[8];
#pragma unroll
        for (int d = 0; d < 4; ++d) {
            h[2 * d]     = acc[2 * d]     + __uint_as_float(cu[d] << 16);
            h[2 * d + 1] = acc[2 * d + 1] + __uint_as_float(cu[d] & 0xffff0000u);
        }
        uint4 ov;
        bf16* o8 = reinterpret_cast<bf16*>(&ov);
#pragma unroll
        for (int i = 0; i < 8; ++i) {
            o8[i] = __float2bfloat16(h[i]);
            s1w += h[i];
            s2w += h[i] * h[i];
        }
        if (el == 0) reinterpret_cast<uint4*>(cmb)[(size_t)node * 16 + fb] = ov;

        node = nxt; start = nstart; deg = ndeg;
    }
#undef ACC8

    // Fold stats across feature blocks (lane bits 0..3); el groups hold
    // identical values, so lane 0's sum is the full 128-feature total.
#pragma unroll
    for (int m = 1; m < 16; m <<= 1) {
        s1w += __shfl_xor(s1w, m);
        s2w += __shfl_xor(s2w, m);
    }
    if (lane == 0) {
        int bkt = wid & 255;
        atomicAdd(&buckets[layer * 512 + bkt * 2],     s1w);
        atomicAdd(&buckets[layer * 512 + bkt * 2 + 1], s2w);
    }
}

// ---------------------------------------------------------------------------
// Final normalize + affine + leaky_relu + residual (layer 2 only).
// Stats reduced inline from buckets. Writes d_out in the detected dtype.
// ---------------------------------------------------------------------------
__global__ __launch_bounds__(256) void k_norm(
    const bf16* __restrict__ hBuf, bf16* __restrict__ yw,
    const float* __restrict__ buckets, const bf16* __restrict__ prm,
    void* __restrict__ outFinal, const int* __restrict__ flagp, int layer)
{
    __shared__ double redS[8];
    __shared__ float s_mean, s_inv;
    const int tid = threadIdx.x;
    stats_reduce(buckets, layer, tid, redS, &s_mean, &s_inv);
    const float mean  = s_mean;
    const float scale = s_inv;

    const long i = (long)blockIdx.x * 256 + tid;   // < 1,600,000 uint4 chunks

    uint4 hv = reinterpret_cast<const uint4*>(hBuf)[i];
    uint4 yv = reinterpret_cast<const uint4*>(yw)[i];
    const bf16* h8 = reinterpret_cast<const bf16*>(&hv);
    const bf16* y8 = reinterpret_cast<const bf16*>(&yv);
    const int colb = ((int)(i & 15)) * 8;
    const bf16* lnwc = prm + 768  + layer * 128;
    const bf16* lnbc = prm + 1152 + layer * 128;

    float r[8];
    uint4 ov;
    bf16* o8 = reinterpret_cast<bf16*>(&ov);
#pragma unroll
    for (int jj = 0; jj < 8; ++jj) {
        float g = __bfloat162float(lnwc[colb + jj]);
        float b = __bfloat162float(lnbc[colb + jj]);
        float h = (__bfloat162float(h8[jj]) - mean) * scale * g + b;
        h = (h >= 0.f) ? h : SLOPE * h;
        r[jj] = __bfloat162float(y8[jj]) + h;
        o8[jj] = __float2bfloat16(r[jj]);
    }
    if (flagp[0]) {
        reinterpret_cast<uint4*>(outFinal)[i] = ov;
    } else {
        float4 lo = make_float4(r[0], r[1], r[2], r[3]);
        float4 hi = make_float4(r[4], r[5], r[6], r[7]);
        reinterpret_cast<float4*>(outFinal)[2 * i]     = lo;
        reinterpret_cast<float4*>(outFinal)[2 * i + 1] = hi;
    }
}

// ---------------------------------------------------------------------------
// Launch. Workspace ~92 MB. Every buffer is fully recomputed per call.
// ---------------------------------------------------------------------------
extern "C" void kernel_launch(void* const* d_in, const int* in_sizes, int n_in,
                              void* d_out, int out_size, void* d_ws, size_t ws_size,
                              hipStream_t stream)
{
    const void* yIn = d_in[0];
    const int*  ei  = (const int*)d_in[1];
    const void* W1  = d_in[2];
    const void* b1  = d_in[3];
    const void* W2  = d_in[4];
    const void* W3  = d_in[5];
    const void* b3  = d_in[6];
    const void* lnw = d_in[7];
    const void* lnb = d_in[8];

    char* ws = (char*)d_ws;
    size_t o = 0;
    auto alloc = [&](size_t bytes) -> char* {
        char* p = ws + o;
        o += (bytes + 255) & ~(size_t)255;
        return p;
    };
    bf16* yw     = (bf16*)alloc((size_t)M_TOT * 2);          // 25.6 MB
    bf16* aBuf   = (bf16*)alloc((size_t)M_TOT * 2);          // 25.6 MB
    bf16* cmb    = (bf16*)alloc((size_t)M_TOT * 2);          // 25.6 MB (also holds h)
    bf16* Wt     = (bf16*)alloc((size_t)9 * 16384 * 2);      // 0.3 MB
    bf16* prm    = (bf16*)alloc((size_t)1536 * 2);
    int*  edst   = (int*)alloc((size_t)N_EDGES * 4);         // 6.4 MB
    int*  binned = (int*)alloc((size_t)N_EDGES * 4);         // 6.4 MB
    int*  histG  = (int*)alloc((size_t)NBIN * HG * 4);       // 0.8 MB
    int*  binTot = (int*)alloc((size_t)NBIN * 4);
    int*  binSta = (int*)alloc((size_t)NBIN * 4);
    int*  offs   = (int*)alloc((size_t)N_NODES * 4);         // 0.4 MB
    int*  degcnt = (int*)alloc((size_t)N_NODES * 4);         // 0.4 MB
    const int nz = 3 * 512 + 8;                              // buckets|flag
    int* zr = (int*)alloc((size_t)nz * 4);
    float* buckets = (float*)zr;
    int*   flagp   = zr + 3 * 512;

    k_detect <<<1, 256, 0, stream>>>((const unsigned int*)yIn, flagp, zr);
    k_hist   <<<HG, 256, 0, stream>>>(yIn, yw, flagp, ei, histG);
    k_hscan1 <<<NBIN, 512, 0, stream>>>(histG, binTot);
    k_scatter<<<HG, 256, 0, stream>>>(ei, histG, binTot, binSta, binned);
    k_bin    <<<NBIN, 256, 0, stream>>>(binned, binSta, binTot, edst, degcnt, offs);
    k_wt     <<<577, 256, 0, stream>>>(W1, W2, W3, Wt, b1, b3, lnw, lnb, prm, flagp);

    const int ngemm = (N_NODES + GEMM_M - 1) / GEMM_M;
    for (int l = 0; l < 3; ++l) {
        k_gemm3<<<ngemm, 256, 0, stream>>>(yw, cmb, buckets, Wt, prm, degcnt, aBuf, cmb, l);
        k_agg  <<<AGG_BLOCKS, 256, 0, stream>>>(aBuf, cmb, offs, degcnt, edst, buckets, l);
    }
    k_norm<<<M_TOT / (8 * 256), 256, 0, stream>>>(cmb, yw, buckets, prm, d_out, flagp, 2);
}

// Round 9
// 477.055 us; speedup vs baseline: 1.1434x; 1.1434x over previous
//
#include <hip/hip_runtime.h>
#include <hip/hip_bf16.h>
#include <math.h>

// Problem constants (fixed by the reference).
#define N_NODES 100000
#define N_EDGES 1600000
#define DF      128
#define EPSV    1e-5f
#define SLOPE   0.01f
#define M_TOT   (N_NODES * DF)   // 12,800,000 elements

#define HG    512                // histogram blocks (E/HG = 3125 edges each)
#define EPB   (N_EDGES / HG)     // 3125
#define NBIN  391                // ceil(N_NODES / 256); bin = dst >> 8

typedef __hip_bfloat16 bf16;
typedef __attribute__((ext_vector_type(8))) short short8;   // 8 bf16 = 4 VGPRs (MFMA A/B frag)
typedef __attribute__((ext_vector_type(4))) float f32x4;    // MFMA C/D frag

// ---------------------------------------------------------------------------
// Runtime dtype detection + bucket zeroing.
// ---------------------------------------------------------------------------
__global__ void k_detect(const unsigned int* __restrict__ yw32, int* __restrict__ flagp,
                         int* __restrict__ bucketsI)
{
    __shared__ int cnt;
    const int tid = threadIdx.x;
    if (tid == 0) cnt = 0;
    for (int i = tid; i < 1536; i += 256) bucketsI[i] = 0;
    __syncthreads();
    unsigned w = yw32[tid];                  // 256 words sampled
    int e = (w >> 7) & 0xFF;
    if (e >= 96 && e <= 140) atomicAdd(&cnt, 1);
    __syncthreads();
    if (tid == 0) flagp[0] = (cnt >= 150) ? 1 : 0;   // 1 = bf16 inputs
}

// ---------------------------------------------------------------------------
// Edge decode: handles both int32 and int64 layouts of edge_index[2,E].
// ---------------------------------------------------------------------------
__device__ __forceinline__ void edge_decode(const int* __restrict__ ei, int e,
                                            int& s, int& d)
{
    bool is64 = ((ei[1] | ei[3] | ei[5] | ei[7]) == 0);
    if (is64) { s = ei[2 * e]; d = ei[2 * (N_EDGES + e)]; }
    else      { s = ei[e];     d = ei[N_EDGES + e];       }
}

// ---------------------------------------------------------------------------
// CSR build, pass 1: per-block LDS histogram over 391 coarse bins (dst>>8).
// ZERO global atomics. y -> bf16 conversion fused.
// ---------------------------------------------------------------------------
__global__ __launch_bounds__(256) void k_hist(
    const void* __restrict__ yin, bf16* __restrict__ yw,
    const int* __restrict__ flagp, const int* __restrict__ ei,
    int* __restrict__ histG)
{
    __shared__ int h[NBIN];
    const int tid = threadIdx.x, b = blockIdx.x;
    for (int i = tid; i < NBIN; i += 256) h[i] = 0;
    __syncthreads();

    const int e0 = b * EPB;
    for (int e = e0 + tid; e < e0 + EPB; e += 256) {
        int s, d;
        edge_decode(ei, e, s, d);
        if ((unsigned)s < N_NODES && (unsigned)d < N_NODES)
            atomicAdd(&h[d >> 8], 1);
    }

    // Fused cvt: grid-stride over 1.6M uint4 chunks (8 bf16 each).
    const int isbf = flagp[0];
    for (long t = (long)b * 256 + tid; t < (M_TOT / 8); t += (long)HG * 256) {
        float f[8];
        if (isbf) {
            uint4 v = reinterpret_cast<const uint4*>(yin)[t];
            const bf16* sp = reinterpret_cast<const bf16*>(&v);
#pragma unroll
            for (int j = 0; j < 8; ++j) f[j] = __bfloat162float(sp[j]);
        } else {
            float4 v0 = reinterpret_cast<const float4*>(yin)[2 * t];
            float4 v1 = reinterpret_cast<const float4*>(yin)[2 * t + 1];
            f[0] = v0.x; f[1] = v0.y; f[2] = v0.z; f[3] = v0.w;
            f[4] = v1.x; f[5] = v1.y; f[6] = v1.z; f[7] = v1.w;
        }
        uint4 ov;
        bf16* o = reinterpret_cast<bf16*>(&ov);
#pragma unroll
        for (int j = 0; j < 8; ++j) {
            float x = f[j];
            if (!isfinite(x)) x = 0.f;
            o[j] = __float2bfloat16(x);
        }
        reinterpret_cast<uint4*>(yw)[t] = ov;
    }

    __syncthreads();
    for (int i = tid; i < NBIN; i += 256) histG[i * HG + b] = h[i];
}

// Pass 2: per-bin exclusive scan over the 512 blocks (in place) + bin total.
__global__ void k_hscan1(int* __restrict__ histG, int* __restrict__ binTotal)
{
    __shared__ int sc[512];
    const int bin = blockIdx.x, tid = threadIdx.x;
    int v = histG[bin * HG + tid];
    sc[tid] = v;
    __syncthreads();
    for (int off = 1; off < 512; off <<= 1) {
        int t = (tid >= off) ? sc[tid - off] : 0;
        __syncthreads();
        sc[tid] += t;
        __syncthreads();
    }
    histG[bin * HG + tid] = sc[tid] - v;      // exclusive over blocks
    if (tid == 511) binTotal[bin] = sc[511];
}

// Pass 3: inline bin-total scan; scatter packed (dstLow8<<17 | src).
__global__ __launch_bounds__(256) void k_scatter(
    const int* __restrict__ ei, const int* __restrict__ histG,
    const int* __restrict__ binTotal, int* __restrict__ binStart,
    int* __restrict__ binned)
{
    __shared__ int sc[512];
    __shared__ int base[NBIN];
    __shared__ int cur[NBIN];
    const int tid = threadIdx.x, b = blockIdx.x;

    {
        int v0 = (tid < NBIN) ? binTotal[tid] : 0;
        int v1 = (tid + 256 < NBIN) ? binTotal[tid + 256] : 0;
        sc[tid] = v0; sc[tid + 256] = v1;
        __syncthreads();
        for (int off = 1; off < 512; off <<= 1) {
            int a  = (tid >= off) ? sc[tid - off] : 0;
            int b2 = (tid + 256 >= off) ? sc[tid + 256 - off] : 0;
            __syncthreads();
            sc[tid] += a; sc[tid + 256] += b2;
            __syncthreads();
        }
    }
    for (int i = tid; i < NBIN; i += 256) {
        int ex = sc[i] - binTotal[i];         // exclusive prefix
        base[i] = ex + histG[i * HG + b];
        cur[i]  = 0;
        if (b == 0) binStart[i] = ex;         // publish for k_bin
    }
    __syncthreads();

    const int e0 = b * EPB;
    for (int e = e0 + tid; e < e0 + EPB; e += 256) {
        int s, d;
        edge_decode(ei, e, s, d);
        if ((unsigned)s < N_NODES && (unsigned)d < N_NODES) {
            int bin = d >> 8;
            int r = atomicAdd(&cur[bin], 1);
            binned[base[bin] + r] = ((d & 255) << 17) | s;
        }
    }
}

// Pass 4: one block per bin -> exact per-node CSR (degcnt, offs, edst).
__global__ __launch_bounds__(256) void k_bin(
    const int* __restrict__ binned, const int* __restrict__ binStart,
    const int* __restrict__ binTotal, int* __restrict__ edst,
    int* __restrict__ degcnt, int* __restrict__ offs)
{
    __shared__ int hloc[256];
    __shared__ int lofs[256];
    __shared__ int sc[256];
    const int bin = blockIdx.x, tid = threadIdx.x;
    const int bbase = binStart[bin], cnt = binTotal[bin];

    hloc[tid] = 0;
    __syncthreads();
    for (int i = tid; i < cnt; i += 256)
        atomicAdd(&hloc[binned[bbase + i] >> 17], 1);
    __syncthreads();

    const int deg = hloc[tid];
    sc[tid] = deg;
    __syncthreads();
    for (int off = 1; off < 256; off <<= 1) {
        int t = (tid >= off) ? sc[tid - off] : 0;
        __syncthreads();
        sc[tid] += t;
        __syncthreads();
    }
    const int ex = sc[tid] - deg;
    lofs[tid] = ex;
    const int node = bin * 256 + tid;
    if (node < N_NODES) {
        degcnt[node] = deg;
        offs[node]   = bbase + ex;
    }
    hloc[tid] = 0;          // reuse as per-node cursor
    __syncthreads();

    for (int i = tid; i < cnt; i += 256) {
        int v = binned[bbase + i];
        int n = v >> 17;
        int r = atomicAdd(&hloc[n], 1);
        edst[bbase + lofs[n] + r] = v & 0x1FFFF;
    }
}

// ---------------------------------------------------------------------------
// Weights convert+transpose (W[l][k][n] -> Wt[mat][n][k]) for MFMA B.
// Block 576 additionally packs the small params.
// ---------------------------------------------------------------------------
__global__ void k_wt(const void* __restrict__ W1, const void* __restrict__ W2,
                     const void* __restrict__ W3, bf16* __restrict__ Wt,
                     const void* __restrict__ b1, const void* __restrict__ b3,
                     const void* __restrict__ lnw, const void* __restrict__ lnb,
                     bf16* __restrict__ prm, const int* __restrict__ flagp)
{
    const int isbf = flagp[0];
    if (blockIdx.x == 576) {
        for (int i = threadIdx.x; i < 1536; i += 256) {
            int which = i / 384, r = i - which * 384;
            const void* src = (which == 0) ? b1 : (which == 1) ? b3
                            : (which == 2) ? lnw : lnb;
            float v = isbf ? __bfloat162float(reinterpret_cast<const bf16*>(src)[r])
                           : reinterpret_cast<const float*>(src)[r];
            if (!isfinite(v)) v = 0.f;
            prm[i] = __float2bfloat16(v);
        }
        return;
    }
    int idx = blockIdx.x * 256 + threadIdx.x;      // < 9*16384 = 147456
    int mat = idx >> 14;
    int r   = idx & 16383;
    int k   = r >> 7, n = r & 127;
    int l = mat / 3, which = mat - l * 3;
    const void* src = (which == 0) ? W1 : (which == 1 ? W2 : W3);
    size_t ofs = (size_t)l * 16384 + (size_t)k * 128 + n;
    float v = isbf ? __bfloat162float(reinterpret_cast<const bf16*>(src)[ofs])
                   : reinterpret_cast<const float*>(src)[ofs];
    if (!isfinite(v)) v = 0.f;
    Wt[((size_t)mat << 14) + (size_t)n * 128 + k] = __float2bfloat16(v);
}

// ---------------------------------------------------------------------------
// Inline LN-stats reduce: 256 threads fold the 256 bucket pairs of `layer`
// into {mean, inv} broadcast via LDS.
// ---------------------------------------------------------------------------
__device__ __forceinline__ void stats_reduce(
    const float* __restrict__ buckets, int layer, int tid,
    double* redS, float* s_mean, float* s_inv)
{
    double s1 = (double)buckets[layer * 512 + tid * 2];
    double s2 = (double)buckets[layer * 512 + tid * 2 + 1];
#pragma unroll
    for (int m = 1; m < 64; m <<= 1) {
        s1 += __shfl_xor(s1, m);
        s2 += __shfl_xor(s2, m);
    }
    const int wv = tid >> 6;
    if ((tid & 63) == 0) { redS[wv] = s1; redS[4 + wv] = s2; }
    __syncthreads();
    if (tid == 0) {
        double S1 = redS[0] + redS[1] + redS[2] + redS[3];
        double S2 = redS[4] + redS[5] + redS[6] + redS[7];
        double mean, inv;
        if (isfinite(S1) && isfinite(S2)) {
            const double M = (double)M_TOT;
            mean = S1 / M;
            double var = S2 / M - mean * mean;
            if (!(var > 0.0)) var = 0.0;
            inv = 1.0 / (sqrt(var) + (double)EPSV);
        } else {
            mean = 0.0; inv = 1.0;
        }
        *s_mean = (float)mean;
        *s_inv  = (float)inv;
    }
    __syncthreads();
}

// ---------------------------------------------------------------------------
// Fused triple GEMM, 64-row M-tile, A IN REGISTERS (v3).
// The A-staging lane map is chosen to EQUAL the MFMA A-fragment map:
// lane (wave,quad,lm) owns row wave*16+lm, chunks kk*32+quad*8 (kk=0..3).
// So A-frags live in 16 VGPRs; no Asm, no A ds_reads, no A re-read.
// For layer>0 the same lane applies norm+leaky+residual to its own chunks,
// writes yw, and keeps the result as the fragment (no write-read hazard).
// LDS = Bsm only (34.8 KB) -> 4 blocks/CU (16 waves, was 12).
//   pass 1: accB = y@W2 ; pass 2: accC = y@W3 -> cmb = accC + b3 - deg*accB
//   pass 3: accA = y@W1 -> aBuf = accA + b1
// ---------------------------------------------------------------------------
__global__ __launch_bounds__(256, 4) void k_gemm3(
    bf16* __restrict__ yw, const bf16* __restrict__ hprev,
    const float* __restrict__ buckets, const bf16* __restrict__ Wt,
    const bf16* __restrict__ prm, const int* __restrict__ degcnt,
    bf16* __restrict__ aBuf, bf16* __restrict__ cmb, int layer)
{
    __shared__ bf16 Bsm[128][136];    // 34,816 B (+8 pad: bank-conflict-free)
    __shared__ double redS[8];
    __shared__ float s_mean, s_inv;

    const int tid = threadIdx.x;
    const int wave = tid >> 6, lane = tid & 63;
    const int lm = lane & 15, quad = lane >> 4;
    const long r0 = (long)blockIdx.x * 64;
    const long arow = r0 + wave * 16 + lm;     // this lane's A row
    const bool rok = arow < N_NODES;

    short8 afr[4];                             // A fragments, kk = 0..3

    if (layer == 0) {
        const uint4* gy = reinterpret_cast<const uint4*>(yw);
#pragma unroll
        for (int kk = 0; kk < 4; ++kk) {
            uint4 v = make_uint4(0, 0, 0, 0);
            if (rok) v = gy[arow * 16 + (kk * 4 + quad)];
            afr[kk] = *reinterpret_cast<const short8*>(&v);
        }
    } else {
        stats_reduce(buckets, layer - 1, tid, redS, &s_mean, &s_inv);
        const float mean = s_mean;
        const float inv  = s_inv;
        const bf16* lnwc = prm + 768  + (layer - 1) * 128;
        const bf16* lnbc = prm + 1152 + (layer - 1) * 128;
        const uint4* gh = reinterpret_cast<const uint4*>(hprev);
        const uint4* gy = reinterpret_cast<const uint4*>(yw);
#pragma unroll
        for (int kk = 0; kk < 4; ++kk) {
            const int c16  = kk * 4 + quad;       // 16B chunk index
            const int colc = c16 * 8;             // feature column base
            uint4 ov = make_uint4(0, 0, 0, 0);
            if (rok) {
                uint4 hv = gh[arow * 16 + c16];
                uint4 yv = gy[arow * 16 + c16];
                const bf16* h8 = reinterpret_cast<const bf16*>(&hv);
                const bf16* y8 = reinterpret_cast<const bf16*>(&yv);
                bf16* o8 = reinterpret_cast<bf16*>(&ov);
#pragma unroll
                for (int jj = 0; jj < 8; ++jj) {
                    float g = __bfloat162float(lnwc[colc + jj]);
                    float b = __bfloat162float(lnbc[colc + jj]);
                    float hh = (__bfloat162float(h8[jj]) - mean) * inv * g + b;
                    hh = (hh >= 0.f) ? hh : SLOPE * hh;
                    o8[jj] = __float2bfloat16(__bfloat162float(y8[jj]) + hh);
                }
                reinterpret_cast<uint4*>(yw)[arow * 16 + c16] = ov;
            }
            afr[kk] = *reinterpret_cast<const short8*>(&ov);
        }
    }

#define STAGE_B(MATIDX)                                                          \
    {                                                                            \
        const uint4* gw = reinterpret_cast<const uint4*>(Wt + ((size_t)(MATIDX) << 14)); \
        _Pragma("unroll")                                                        \
        for (int it = 0; it < 8; ++it) {                                         \
            int chunk = it * 256 + tid;                                          \
            *reinterpret_cast<uint4*>(&Bsm[chunk >> 4][(chunk & 15) * 8]) = gw[chunk]; \
        }                                                                        \
    }

    f32x4 accB[8];
#pragma unroll
    for (int nt = 0; nt < 8; ++nt) accB[nt] = (f32x4){0.f, 0.f, 0.f, 0.f};

    // ---- pass 1: W2 ----
    STAGE_B(layer * 3 + 1);
    __syncthreads();
#pragma unroll
    for (int kk = 0; kk < 4; ++kk) {
        const int kb = kk * 32 + quad * 8;
#pragma unroll
        for (int nt = 0; nt < 8; ++nt) {
            short8 bfr = *reinterpret_cast<const short8*>(&Bsm[nt * 16 + lm][kb]);
            accB[nt] = __builtin_amdgcn_mfma_f32_16x16x32_bf16(afr[kk], bfr, accB[nt], 0, 0, 0);
        }
    }
    __syncthreads();

    // ---- pass 2: W3 ----
    STAGE_B(layer * 3 + 2);
    __syncthreads();
    f32x4 accC[8];
#pragma unroll
    for (int nt = 0; nt < 8; ++nt) accC[nt] = (f32x4){0.f, 0.f, 0.f, 0.f};
#pragma unroll
    for (int kk = 0; kk < 4; ++kk) {
        const int kb = kk * 32 + quad * 8;
#pragma unroll
        for (int nt = 0; nt < 8; ++nt) {
            short8 bfr = *reinterpret_cast<const short8*>(&Bsm[nt * 16 + lm][kb]);
            accC[nt] = __builtin_amdgcn_mfma_f32_16x16x32_bf16(afr[kk], bfr, accC[nt], 0, 0, 0);
        }
    }

    // cmb epilogue.  C/D layout: col = lane&15, row = quad*4 + reg.
    const bf16* b3c = prm + 384 + layer * 128;
#pragma unroll
    for (int i = 0; i < 4; ++i) {
        long row = r0 + wave * 16 + quad * 4 + i;
        if (row < N_NODES) {
            float degf = (float)degcnt[row];
#pragma unroll
            for (int nt = 0; nt < 8; ++nt) {
                int col = nt * 16 + lm;
                float v = accC[nt][i] + __bfloat162float(b3c[col]) - degf * accB[nt][i];
                cmb[row * 128 + col] = __float2bfloat16(v);
            }
        }
    }
    __syncthreads();

    // ---- pass 3: W1 (reuse accB) ----
    STAGE_B(layer * 3 + 0);
    __syncthreads();
#pragma unroll
    for (int nt = 0; nt < 8; ++nt) accB[nt] = (f32x4){0.f, 0.f, 0.f, 0.f};
#pragma unroll
    for (int kk = 0; kk < 4; ++kk) {
        const int kb = kk * 32 + quad * 8;
#pragma unroll
        for (int nt = 0; nt < 8; ++nt) {
            short8 bfr = *reinterpret_cast<const short8*>(&Bsm[nt * 16 + lm][kb]);
            accB[nt] = __builtin_amdgcn_mfma_f32_16x16x32_bf16(afr[kk], bfr, accB[nt], 0, 0, 0);
        }
    }
    const bf16* b1c = prm + layer * 128;
#pragma unroll
    for (int i = 0; i < 4; ++i) {
        long row = r0 + wave * 16 + quad * 4 + i;
        if (row < N_NODES) {
#pragma unroll
            for (int nt = 0; nt < 8; ++nt) {
                int col = nt * 16 + lm;
                aBuf[row * 128 + col] =
                    __float2bfloat16(accB[nt][i] + __bfloat162float(b1c[col]));
            }
        }
    }
#undef STAGE_B
}

// ---------------------------------------------------------------------------
// Edge aggregation + h assembly (in place over cmb) + LN partial stats.
// R7 config (best measured: 67 us): row-major uint4 gathers, persistent
// waves, 4-deep ILP, cross-node rotation prefetch, deferred stats.
// ---------------------------------------------------------------------------
#define AGG_BLOCKS 2048
#define AGG_WAVES  (AGG_BLOCKS * 4)

__global__ __launch_bounds__(256, 8) void k_agg(
    const bf16* __restrict__ aBuf, bf16* __restrict__ cmb,
    const int* __restrict__ offs, const int* __restrict__ degcnt,
    const int* __restrict__ edst, float* __restrict__ buckets, int layer)
{
    const int tid  = threadIdx.x;
    const int lane = tid & 63;
    const int el   = lane >> 4;         // edge slot (0..3)
    const int fb   = lane & 15;         // feature block (8 bf16 = 16 B)
    const int wid  = __builtin_amdgcn_readfirstlane((int)(blockIdx.x * 4) + (tid >> 6));

    const uint4* A4 = reinterpret_cast<const uint4*>(aBuf);

    float s1w = 0.f, s2w = 0.f;         // per-lane LN stats over all our nodes

#define ACC8(v)                                                                \
    {                                                                          \
        const unsigned* _u = reinterpret_cast<const unsigned*>(&(v));          \
        _Pragma("unroll")                                                      \
        for (int _d = 0; _d < 4; ++_d) {                                       \
            acc[2 * _d]     += __uint_as_float(_u[_d] << 16);                  \
            acc[2 * _d + 1] += __uint_as_float(_u[_d] & 0xffff0000u);          \
        }                                                                      \
    }

    int node  = wid;                      // wid < 8192 << N_NODES, always valid
    int start = offs[node];
    int deg   = degcnt[node];
    while (node < N_NODES) {
        // Rotation prefetch: next node's CSR header resolves under this
        // node's gather chain.
        const int nxt = node + AGG_WAVES;
        int nstart = 0, ndeg = 0;
        if (nxt < N_NODES) { nstart = offs[nxt]; ndeg = degcnt[nxt]; }

        // Prefetch this node's cmb row (issues before the gather chain).
        const uint4 cv = reinterpret_cast<const uint4*>(cmb)[(size_t)node * 16 + fb];

        float acc[8];
#pragma unroll
        for (int i = 0; i < 8; ++i) acc[i] = 0.f;

        // Lane slot el covers indices j = el, el+4, el+8, ... (< deg).
        int j = el;
        for (; j + 12 < deg; j += 16) {       // 4 gathers in flight
            int e0 = edst[start + j];
            int e1 = edst[start + j + 4];
            int e2 = edst[start + j + 8];
            int e3 = edst[start + j + 12];
            uint4 v0 = A4[(size_t)e0 * 16 + fb];
            uint4 v1 = A4[(size_t)e1 * 16 + fb];
            uint4 v2 = A4[(size_t)e2 * 16 + fb];
            uint4 v3 = A4[(size_t)e3 * 16 + fb];
            ACC8(v0); ACC8(v1); ACC8(v2); ACC8(v3);
        }
        if (j + 4 < deg) {                    // 2 gathers in flight
            int e0 = edst[start + j];
            int e1 = edst[start + j + 4];
            uint4 v0 = A4[(size_t)e0 * 16 + fb];
            uint4 v1 = A4[(size_t)e1 * 16 + fb];
            ACC8(v0); ACC8(v1);
            j += 8;
        }
        if (j < deg) {                        // last single
            int e0 = edst[start + j];
            uint4 v0 = A4[(size_t)e0 * 16 + fb];
            ACC8(v0);
        }

        // Reduce across the 4 edge slots (lane bits 4,5).
#pragma unroll
        for (int i = 0; i < 8; ++i) {
            acc[i] += __shfl_xor(acc[i], 16);
            acc[i] += __shfl_xor(acc[i], 32);
        }

        // h = agg + cmb row; all lanes compute (identical across el groups).
        const unsigned* cu = reinterpret_cast<const unsigned*>(&cv);
        float h[8];
#pragma unroll
        for (int d = 0; d < 4; ++d) {
            h[2 * d]     = acc[2 * d]     + __uint_as_float(cu[d] << 16);
            h[2 * d + 1] = acc[2 * d + 1] + __uint_as_float(cu[d] & 0xffff0000u);
        }
        uint4 ov;
        bf16* o8 = reinterpret_cast<bf16*>(&ov);
#pragma unroll
        for (int i = 0; i < 8; ++i) {
            o8[i] = __float2bfloat16(h[i]);
            s1w += h[i];
            s2w += h[i] * h[i];
        }
        if (el == 0) reinterpret_cast<uint4*>(cmb)[(size_t)node * 16 + fb] = ov;

        node = nxt; start = nstart; deg = ndeg;
    }
#undef ACC8

    // Fold stats across feature blocks (lane bits 0..3); el groups hold
    // identical values, so lane 0's sum is the full 128-feature total.
#pragma unroll
    for (int m = 1; m < 16; m <<= 1) {
        s1w += __shfl_xor(s1w, m);
        s2w += __shfl_xor(s2w, m);
    }
    if (lane == 0) {
        int bkt = wid & 255;
        atomicAdd(&buckets[layer * 512 + bkt * 2],     s1w);
        atomicAdd(&buckets[layer * 512 + bkt * 2 + 1], s2w);
    }
}

// ---------------------------------------------------------------------------
// Final normalize + affine + leaky_relu + residual (layer 2 only).
// Stats reduced inline from buckets. Writes d_out in the detected dtype.
// ---------------------------------------------------------------------------
__global__ __launch_bounds__(256) void k_norm(
    const bf16* __restrict__ hBuf, bf16* __restrict__ yw,
    const float* __restrict__ buckets, const bf16* __restrict__ prm,
    void* __restrict__ outFinal, const int* __restrict__ flagp, int layer)
{
    __shared__ double redS[8];
    __shared__ float s_mean, s_inv;
    const int tid = threadIdx.x;
    stats_reduce(buckets, layer, tid, redS, &s_mean, &s_inv);
    const float mean  = s_mean;
    const float scale = s_inv;

    const long i = (long)blockIdx.x * 256 + tid;   // < 1,600,000 uint4 chunks

    uint4 hv = reinterpret_cast<const uint4*>(hBuf)[i];
    uint4 yv = reinterpret_cast<const uint4*>(yw)[i];
    const bf16* h8 = reinterpret_cast<const bf16*>(&hv);
    const bf16* y8 = reinterpret_cast<const bf16*>(&yv);
    const int colb = ((int)(i & 15)) * 8;
    const bf16* lnwc = prm + 768  + layer * 128;
    const bf16* lnbc = prm + 1152 + layer * 128;

    float r[8];
    uint4 ov;
    bf16* o8 = reinterpret_cast<bf16*>(&ov);
#pragma unroll
    for (int jj = 0; jj < 8; ++jj) {
        float g = __bfloat162float(lnwc[colb + jj]);
        float b = __bfloat162float(lnbc[colb + jj]);
        float h = (__bfloat162float(h8[jj]) - mean) * scale * g + b;
        h = (h >= 0.f) ? h : SLOPE * h;
        r[jj] = __bfloat162float(y8[jj]) + h;
        o8[jj] = __float2bfloat16(r[jj]);
    }
    if (flagp[0]) {
        reinterpret_cast<uint4*>(outFinal)[i] = ov;
    } else {
        float4 lo = make_float4(r[0], r[1], r[2], r[3]);
        float4 hi = make_float4(r[4], r[5], r[6], r[7]);
        reinterpret_cast<float4*>(outFinal)[2 * i]     = lo;
        reinterpret_cast<float4*>(outFinal)[2 * i + 1] = hi;
    }
}

// ---------------------------------------------------------------------------
// Launch. Workspace ~92 MB. Every buffer is fully recomputed per call.
// ---------------------------------------------------------------------------
extern "C" void kernel_launch(void* const* d_in, const int* in_sizes, int n_in,
                              void* d_out, int out_size, void* d_ws, size_t ws_size,
                              hipStream_t stream)
{
    const void* yIn = d_in[0];
    const int*  ei  = (const int*)d_in[1];
    const void* W1  = d_in[2];
    const void* b1  = d_in[3];
    const void* W2  = d_in[4];
    const void* W3  = d_in[5];
    const void* b3  = d_in[6];
    const void* lnw = d_in[7];
    const void* lnb = d_in[8];

    char* ws = (char*)d_ws;
    size_t o = 0;
    auto alloc = [&](size_t bytes) -> char* {
        char* p = ws + o;
        o += (bytes + 255) & ~(size_t)255;
        return p;
    };
    bf16* yw     = (bf16*)alloc((size_t)M_TOT * 2);          // 25.6 MB
    bf16* aBuf   = (bf16*)alloc((size_t)M_TOT * 2);          // 25.6 MB
    bf16* cmb    = (bf16*)alloc((size_t)M_TOT * 2);          // 25.6 MB (also holds h)
    bf16* Wt     = (bf16*)alloc((size_t)9 * 16384 * 2);      // 0.3 MB
    bf16* prm    = (bf16*)alloc((size_t)1536 * 2);
    int*  edst   = (int*)alloc((size_t)N_EDGES * 4);         // 6.4 MB
    int*  binned = (int*)alloc((size_t)N_EDGES * 4);         // 6.4 MB
    int*  histG  = (int*)alloc((size_t)NBIN * HG * 4);       // 0.8 MB
    int*  binTot = (int*)alloc((size_t)NBIN * 4);
    int*  binSta = (int*)alloc((size_t)NBIN * 4);
    int*  offs   = (int*)alloc((size_t)N_NODES * 4);         // 0.4 MB
    int*  degcnt = (int*)alloc((size_t)N_NODES * 4);         // 0.4 MB
    const int nz = 3 * 512 + 8;                              // buckets|flag
    int* zr = (int*)alloc((size_t)nz * 4);
    float* buckets = (float*)zr;
    int*   flagp   = zr + 3 * 512;

    k_detect <<<1, 256, 0, stream>>>((const unsigned int*)yIn, flagp, zr);
    k_hist   <<<HG, 256, 0, stream>>>(yIn, yw, flagp, ei, histG);
    k_hscan1 <<<NBIN, 512, 0, stream>>>(histG, binTot);
    k_scatter<<<HG, 256, 0, stream>>>(ei, histG, binTot, binSta, binned);
    k_bin    <<<NBIN, 256, 0, stream>>>(binned, binSta, binTot, edst, degcnt, offs);
    k_wt     <<<577, 256, 0, stream>>>(W1, W2, W3, Wt, b1, b3, lnw, lnb, prm, flagp);

    const int ngemm = (N_NODES + 63) / 64;
    for (int l = 0; l < 3; ++l) {
        k_gemm3<<<ngemm, 256, 0, stream>>>(yw, cmb, buckets, Wt, prm, degcnt, aBuf, cmb, l);
        k_agg  <<<AGG_BLOCKS, 256, 0, stream>>>(aBuf, cmb, offs, degcnt, edst, buckets, l);
    }
    k_norm<<<M_TOT / (8 * 256), 256, 0, stream>>>(cmb, yw, buckets, prm, d_out, flagp, 2);
}